// Round 5
// baseline (253.944 us; speedup 1.0000x reference)
//
#include <hip/hip_runtime.h>
#include <math.h>

#define NT 20000
#define NW 5000
#define NS 1000

typedef __attribute__((ext_vector_type(8))) short bf16x8;
typedef __attribute__((ext_vector_type(4))) float f32x4;

// ---------------- segment tables ----------------
struct GemmSeg { const short* X; const short* Wt; short* Y; int N; int blk0; };
struct GemmTab { GemmSeg s[10]; int nseg; };

struct GatSeg { const int* rowp; const int* col; const short* xl; const short* xr;
                const float* att; const float* bias; float* agg; int Nd; int wave0; };
struct GatTab { GatSeg s[5]; int nseg; };

struct EdgeSeg { const int* ei; int* cnt; int* col; int E; int blk0; };
struct EdgeTab { EdgeSeg s[5]; int nseg; };

struct ScanTab { int* cnt[5]; int* rowp[5]; int n[5]; };

// ---------------- helpers ----------------
__device__ __forceinline__ float wsum64(float v) {
  #pragma unroll
  for (int o = 32; o > 0; o >>= 1) v += __shfl_xor(v, o, 64);
  return v;
}
__device__ __forceinline__ short f2b(float f) {   // f32 -> bf16 RNE
  unsigned u = __float_as_uint(f);
  unsigned r = (u + 0x7FFFu + ((u >> 16) & 1u)) >> 16;
  return (short)(unsigned short)r;
}
__device__ __forceinline__ float blo(unsigned x) { return __uint_as_float(x << 16); }
__device__ __forceinline__ float bhi(unsigned x) { return __uint_as_float(x & 0xFFFF0000u); }

// ---------------- weight prep: f32 [k][col] -> bf16 [col][k]; also zeroes nxtAll ----
__global__ void wprep_kernel(const float* __restrict__ gWl, const float* __restrict__ gWr,
                             short* __restrict__ Wlt, short* __restrict__ Wrt,
                             int* __restrict__ nxtAll, int nZero) {
  int idx = blockIdx.x * 256 + threadIdx.x;           // 0 .. 327679
  if (idx < nZero) nxtAll[idx] = 0;
  int side = idx >= 163840;
  int j = idx - side * 163840;
  int m = j >> 14;                                    // matrix 0..9
  int e = j & 16383;
  int k = e >> 8, colv = e & 255;
  const float* src = side ? gWr : gWl;
  short* dst = side ? Wrt : Wlt;
  dst[m * 16384 + colv * 64 + k] = f2b(src[m * 16384 + e]);
}

// ---------------- embed (all 3 types, 1 dispatch): y = relu(LN(x@W+b)*g+beta) -------
__global__ void embed_kernel(const float* __restrict__ xT, const float* __restrict__ xW,
                             const float* __restrict__ xS,
                             const float* __restrict__ WT, const float* __restrict__ WW,
                             const float* __restrict__ WS,
                             const float* __restrict__ pT, const float* __restrict__ pW,
                             const float* __restrict__ pS,   // packed b,g,beta: 3*64 each
                             float* __restrict__ yT, float* __restrict__ yW,
                             float* __restrict__ yS,
                             short* __restrict__ bT, short* __restrict__ bW,
                             short* __restrict__ bS) {
  int gid  = blockIdx.x * blockDim.x + threadIdx.x;
  int wid  = gid >> 6;
  int lane = gid & 63;
  const float* x; const float* W; const float* pp; float* y; short* yb; int FD; int n;
  if (wid < NT)            { x = xT; W = WT; pp = pT; y = yT; yb = bT; FD = 16; n = wid; }
  else if (wid < NT + NW)  { x = xW; W = WW; pp = pW; y = yW; yb = bW; FD = 12; n = wid - NT; }
  else if (wid < NT + NW + NS) { x = xS; W = WS; pp = pS; y = yS; yb = bS; FD = 10; n = wid - NT - NW; }
  else return;
  const float* xr = x + (size_t)n * FD;
  float acc = pp[lane];
  for (int k = 0; k < FD; ++k) acc = fmaf(xr[k], W[k * 64 + lane], acc);
  float m = wsum64(acc) * (1.f / 64.f);
  float d = acc - m;
  float v = wsum64(d * d) * (1.f / 64.f);
  float o = d * rsqrtf(v + 1e-5f) * pp[64 + lane] + pp[128 + lane];
  o = fmaxf(o, 0.f);
  y[(size_t)n * 64 + lane] = o;
  yb[(size_t)n * 64 + lane] = f2b(o);
}

// pack b,g,beta into contiguous 192 floats per type
__global__ void packp_kernel(const float* b0, const float* g0, const float* be0,
                             const float* b1, const float* g1, const float* be1,
                             const float* b2, const float* g2, const float* be2,
                             float* __restrict__ out) {
  int i = threadIdx.x;   // 0..63
  out[i]       = b0[i];  out[64 + i]  = g0[i];  out[128 + i] = be0[i];
  out[192 + i] = b1[i];  out[256 + i] = g1[i];  out[320 + i] = be1[i];
  out[384 + i] = b2[i];  out[448 + i] = g2[i];  out[512 + i] = be2[i];
}

// ---------------- CSR: count / scan / fill (segmented) ----------------
__global__ void count_kernel(EdgeTab tab) {
  int b = blockIdx.x, si = 0;
  for (int i = 1; i < tab.nseg; ++i) if (b >= tab.s[i].blk0) si = i;
  EdgeSeg sg = tab.s[si];
  int e = (b - sg.blk0) * 256 + threadIdx.x;
  if (e < sg.E) atomicAdd(&sg.cnt[sg.ei[sg.E + e]], 1);
}

__global__ void scan_kernel(ScanTab tab) {
  int t = blockIdx.x;
  int* cnt = tab.cnt[t]; int* rowp = tab.rowp[t]; int n = tab.n[t];
  __shared__ int wsums[16];
  __shared__ int carry_s;
  int tid = threadIdx.x, lane = tid & 63, w = tid >> 6;
  if (tid == 0) carry_s = 0;
  __syncthreads();
  for (int base = 0; base < n; base += 1024) {
    int i = base + tid;
    int v = (i < n) ? cnt[i] : 0;
    int s = v;
    #pragma unroll
    for (int o = 1; o < 64; o <<= 1) { int x = __shfl_up(s, o, 64); if (lane >= o) s += x; }
    if (lane == 63) wsums[w] = s;
    __syncthreads();
    if (w == 0 && lane < 16) {
      int x = wsums[lane];
      #pragma unroll
      for (int o = 1; o < 16; o <<= 1) { int y = __shfl_up(x, o, 16); if (lane >= o) x += y; }
      wsums[lane] = x;
    }
    __syncthreads();
    int carry   = carry_s;
    int waveoff = (w == 0) ? 0 : wsums[w - 1];
    int exc     = carry + waveoff + s - v;
    if (i < n) { rowp[i] = exc; cnt[i] = exc; }
    __syncthreads();
    if (tid == 0) carry_s += wsums[15];
    __syncthreads();
  }
  if (threadIdx.x == 0) rowp[n] = carry_s;
}

__global__ void fill_kernel(EdgeTab tab) {
  int b = blockIdx.x, si = 0;
  for (int i = 1; i < tab.nseg; ++i) if (b >= tab.s[i].blk0) si = i;
  EdgeSeg sg = tab.s[si];
  int e = (b - sg.blk0) * 256 + threadIdx.x;
  if (e >= sg.E) return;
  int s = sg.ei[e], d = sg.ei[sg.E + e];
  int pos = atomicAdd(&sg.cnt[d], 1);
  sg.col[pos] = s;
}

// ---------------- MFMA GEMM: Y[N,256](bf16) = X[N,64](bf16) @ W[64,256] ----------------
// block = 256 thr = 4 waves; tile 64 rows x 256 cols; LDS-repacked coalesced epilogue.
__global__ __launch_bounds__(256) void gemm_kernel(GemmTab tab) {
  __shared__ short lds[4096 + 16896];   // staging 40.96KB >= repack 64*264
  int b = blockIdx.x, si = 0;
  for (int i = 1; i < tab.nseg; ++i) if (b >= tab.s[i].blk0) si = i;
  GemmSeg sg = tab.s[si];
  int r0 = (b - sg.blk0) * 64;
  int tid = threadIdx.x;
  #pragma unroll
  for (int it = 0; it < 2; ++it) {              // stage X tile (8 KB)
    int idx = it * 256 + tid;
    int row = idx >> 3, kq = idx & 7;
    bf16x8 v = {0, 0, 0, 0, 0, 0, 0, 0};
    if (r0 + row < sg.N) v = *(const bf16x8*)&sg.X[(size_t)(r0 + row) * 64 + kq * 8];
    *(bf16x8*)&lds[(row * 8 + (kq ^ (row & 7))) * 8] = v;
  }
  #pragma unroll
  for (int it = 0; it < 8; ++it) {              // stage Wt (32 KB)
    int idx = it * 256 + tid;
    int col = idx >> 3, kq = idx & 7;
    bf16x8 v = *(const bf16x8*)&sg.Wt[col * 64 + kq * 8];
    *(bf16x8*)&lds[4096 + (col * 8 + (kq ^ (col & 7))) * 8] = v;
  }
  __syncthreads();
  int lane = tid & 63, wv = tid >> 6;
  int r = lane & 15, hk = lane >> 4;
  f32x4 acc[4][4];
  #pragma unroll
  for (int rt = 0; rt < 4; ++rt)
    #pragma unroll
    for (int ct = 0; ct < 4; ++ct) acc[rt][ct] = (f32x4){0.f, 0.f, 0.f, 0.f};
  #pragma unroll
  for (int kk = 0; kk < 2; ++kk) {
    int kq = kk * 4 + hk;
    bf16x8 a[4], bb[4];
    #pragma unroll
    for (int rt = 0; rt < 4; ++rt) {
      int row = rt * 16 + r;
      a[rt] = *(const bf16x8*)&lds[(row * 8 + (kq ^ (row & 7))) * 8];
    }
    #pragma unroll
    for (int ct = 0; ct < 4; ++ct) {
      int col = wv * 64 + ct * 16 + r;
      bb[ct] = *(const bf16x8*)&lds[4096 + (col * 8 + (kq ^ (col & 7))) * 8];
    }
    #pragma unroll
    for (int rt = 0; rt < 4; ++rt)
      #pragma unroll
      for (int ct = 0; ct < 4; ++ct)
        acc[rt][ct] = __builtin_amdgcn_mfma_f32_16x16x32_bf16(a[rt], bb[ct], acc[rt][ct], 0, 0, 0);
  }
  __syncthreads();                               // LDS reuse for C repack
  #pragma unroll
  for (int rt = 0; rt < 4; ++rt)
    #pragma unroll
    for (int j = 0; j < 4; ++j) {
      int rowl = rt * 16 + hk * 4 + j;           // C/D: col=lane&15, row=(lane>>4)*4+reg
      #pragma unroll
      for (int ct = 0; ct < 4; ++ct)
        lds[rowl * 264 + wv * 64 + ct * 16 + r] = f2b(acc[rt][ct][j]);
    }
  __syncthreads();
  #pragma unroll
  for (int it = 0; it < 8; ++it) {               // coalesced bf16x8 stores
    int idx = it * 256 + tid;                    // 2048 vec8's
    int row = idx >> 5, v8 = idx & 31;
    if (r0 + row < sg.N) {
      bf16x8 v = *(const bf16x8*)&lds[row * 264 + v8 * 8];
      *(bf16x8*)&sg.Y[(size_t)(r0 + row) * 256 + v8 * 8] = v;
    }
  }
}

// ---------------- GATv2: wave per dst node; batched independent gathers ----------------
__global__ void gat_kernel(GatTab tab) {
  int gwave = (blockIdx.x * blockDim.x + threadIdx.x) >> 6;
  int lane  = threadIdx.x & 63;
  int si = 0;
  for (int i = 1; i < tab.nseg; ++i) if (gwave >= tab.s[i].wave0) si = i;
  GatSeg sg = tab.s[si];
  int n = gwave - sg.wave0;
  if (n >= sg.Nd) return;
  int h = lane >> 4, lig = lane & 15;
  uint2 xru = *(const uint2*)&sg.xr[(size_t)n * 256 + h * 64 + lig * 4];
  float4 a4 = *(const float4*)&sg.att[h * 64 + lig * 4];
  int beg = sg.rowp[n], end = sg.rowp[n + 1];
  int d = end - beg;
  float xr0 = blo(xru.x), xr1 = bhi(xru.x), xr2 = blo(xru.y), xr3 = bhi(xru.y);
  float den = 0.f, c0 = 0.f, c1 = 0.f, c2 = 0.f, c3 = 0.f;
  for (int sc = 0; sc < d; sc += 64) {
    int scn = min(64, d - sc);
    int myc = (lane < scn) ? sg.col[beg + sc + lane] : 0;  // one coalesced edge-list load
    for (int cb = 0; cb < scn; cb += 8) {
      int m = min(8, scn - cb);
      uint2 w[8];
      #pragma unroll
      for (int k = 0; k < 8; ++k)
        if (k < m) {
          int c = __shfl(myc, cb + k, 64);                  // broadcast col
          w[k] = *(const uint2*)&sg.xl[(size_t)c * 256 + h * 64 + lig * 4];
        }
      #pragma unroll
      for (int k = 0; k < 8; ++k)
        if (k < m) {
          float f0 = blo(w[k].x), f1 = bhi(w[k].x), f2v = blo(w[k].y), f3 = bhi(w[k].y);
          float vx = f0 + xr0, vy = f1 + xr1, vz = f2v + xr2, vw = f3 + xr3;
          vx = fmaxf(vx, 0.2f * vx); vy = fmaxf(vy, 0.2f * vy);
          vz = fmaxf(vz, 0.2f * vz); vw = fmaxf(vw, 0.2f * vw);
          float dd = fmaf(vx, a4.x, fmaf(vy, a4.y, fmaf(vz, a4.z, vw * a4.w)));
          dd += __shfl_xor(dd, 1, 64);
          dd += __shfl_xor(dd, 2, 64);
          dd += __shfl_xor(dd, 4, 64);
          dd += __shfl_xor(dd, 8, 64);
          float e = __expf(dd);                // softmax shift-invariant; logits O(10)
          den += e;
          c0 = fmaf(e, f0, c0); c1 = fmaf(e, f1, c1);
          c2 = fmaf(e, f2v, c2); c3 = fmaf(e, f3, c3);
        }
    }
  }
  float4 o = make_float4(0.f, 0.f, 0.f, 0.f);
  if (d > 0) {
    float inv = 1.f / den;
    o.x = c0 * inv; o.y = c1 * inv; o.z = c2 * inv; o.w = c3 * inv;
  }
  o.x += __shfl_xor(o.x, 16, 64); o.x += __shfl_xor(o.x, 32, 64);
  o.y += __shfl_xor(o.y, 16, 64); o.y += __shfl_xor(o.y, 32, 64);
  o.z += __shfl_xor(o.z, 16, 64); o.z += __shfl_xor(o.z, 32, 64);
  o.w += __shfl_xor(o.w, 16, 64); o.w += __shfl_xor(o.w, 32, 64);
  if (lane < 16) {
    float4 b4 = *(const float4*)&sg.bias[lane * 4];
    float4 res;
    res.x = fmaf(0.25f, o.x, b4.x); res.y = fmaf(0.25f, o.y, b4.y);
    res.z = fmaf(0.25f, o.z, b4.z); res.w = fmaf(0.25f, o.w, b4.w);
    *(float4*)&sg.agg[(size_t)n * 64 + lane * 4] = res;
  }
}

// ---------------- combine (float4): out = relu(sum aggs) + x ----------------
__global__ void combine_kernel(const float4* __restrict__ aT0, const float4* __restrict__ aT2,
                               const float4* __restrict__ aT3, const float4* __restrict__ aW,
                               const float4* __restrict__ aS,
                               const float4* __restrict__ xT, const float4* __restrict__ xW,
                               const float4* __restrict__ xS,
                               float4* __restrict__ oT, float4* __restrict__ oW,
                               float4* __restrict__ oS,
                               unsigned* __restrict__ bT, unsigned* __restrict__ bW,
                               unsigned* __restrict__ bS) {
  int i = blockIdx.x * 256 + threadIdx.x;
  const int nT4 = NT * 16, nW4 = NW * 16, nS4 = NS * 16;
  const float4* a; const float4* x; float4* o; unsigned* bo; int j; bool sum3 = false;
  const float4 *a2 = nullptr, *a3 = nullptr;
  if (i < nT4)                 { a = aT0; a2 = aT2; a3 = aT3; x = xT; o = oT; bo = bT; j = i; sum3 = true; }
  else if (i < nT4 + nW4)      { a = aW; x = xW; o = oW; bo = bW; j = i - nT4; }
  else if (i < nT4 + nW4 + nS4){ a = aS; x = xS; o = oS; bo = bS; j = i - nT4 - nW4; }
  else return;
  float4 av = a[j];
  if (sum3) {
    float4 v2 = a2[j], v3 = a3[j];
    av.x += v2.x + v3.x; av.y += v2.y + v3.y; av.z += v2.z + v3.z; av.w += v2.w + v3.w;
  }
  float4 xv = x[j];
  float4 r;
  r.x = fmaxf(av.x, 0.f) + xv.x; r.y = fmaxf(av.y, 0.f) + xv.y;
  r.z = fmaxf(av.z, 0.f) + xv.z; r.w = fmaxf(av.w, 0.f) + xv.w;
  o[j] = r;
  if (bo) {
    unsigned lo = (unsigned)(unsigned short)f2b(r.x) | ((unsigned)(unsigned short)f2b(r.y) << 16);
    unsigned hi = (unsigned)(unsigned short)f2b(r.z) | ((unsigned)(unsigned short)f2b(r.w) << 16);
    bo[j * 2] = lo; bo[j * 2 + 1] = hi;
  }
}

// ---------------- pool (two-stage) ----------------
__global__ __launch_bounds__(256) void pool1_kernel(const float* __restrict__ xt,
                                                    const float* __restrict__ xw,
                                                    const float* __restrict__ xs,
                                                    float* __restrict__ part_sum,
                                                    float* __restrict__ part_max) {
  int b = blockIdx.x;
  const float* x; int N, base, nb;
  if (b < 80)       { x = xt; N = NT; base = 0;   nb = 80; }
  else if (b < 100) { x = xw; N = NW; base = 80;  nb = 20; }
  else              { x = xs; N = NS; base = 100; nb = 4;  }
  int local = b - base;
  int lane = threadIdx.x & 63, w = threadIdx.x >> 6;
  int waveIdx = local * 4 + w, stride = nb * 4;
  float s = 0.f, mx = -3e38f;
  for (int r = waveIdx; r < N; r += stride) {
    float v = x[(size_t)r * 64 + lane];
    s += v; mx = fmaxf(mx, v);
  }
  __shared__ float ss[4][64], sm[4][64];
  ss[w][lane] = s; sm[w][lane] = mx;
  __syncthreads();
  if (w == 0) {
    #pragma unroll
    for (int i = 1; i < 4; ++i) { s += ss[i][lane]; mx = fmaxf(mx, sm[i][lane]); }
    part_sum[(size_t)b * 64 + lane] = s;
    part_max[(size_t)b * 64 + lane] = mx;
  }
}

__global__ void pool2_kernel(const float* __restrict__ part_sum,
                             const float* __restrict__ part_max,
                             float* __restrict__ gc) {
  int b = blockIdx.x;  // 0 station, 1 task, 2 worker
  int lane = threadIdx.x & 63, w = threadIdx.x >> 6;
  int off, cnt, N, mi;
  if (b == 0)      { off = 100; cnt = 4;  N = NS; mi = 0;   }
  else if (b == 1) { off = 0;   cnt = 80; N = NT; mi = 64;  }
  else             { off = 80;  cnt = 20; N = NW; mi = 128; }
  float s = 0.f, mx = -3e38f;
  for (int i = w; i < cnt; i += 4) {
    s += part_sum[(size_t)(off + i) * 64 + lane];
    mx = fmaxf(mx, part_max[(size_t)(off + i) * 64 + lane]);
  }
  __shared__ float ss[4][64], sm[4][64];
  ss[w][lane] = s; sm[w][lane] = mx;
  __syncthreads();
  if (w == 0) {
    #pragma unroll
    for (int i = 1; i < 4; ++i) { s += ss[i][lane]; mx = fmaxf(mx, sm[i][lane]); }
    gc[mi + lane] = s / (float)N;
    gc[192 + mi + lane] = mx;
  }
}

// ---------------- driver ----------------
extern "C" void kernel_launch(void* const* d_in, const int* in_sizes, int n_in,
                              void* d_out, int out_size, void* d_ws, size_t ws_size,
                              hipStream_t stream) {
  const float* x_in[3] = {(const float*)d_in[0], (const float*)d_in[1], (const float*)d_in[2]};
  const int*   ei[5]   = {(const int*)d_in[3], (const int*)d_in[4], (const int*)d_in[5],
                          (const int*)d_in[6], (const int*)d_in[7]};
  const float* Wemb[3] = {(const float*)d_in[8],  (const float*)d_in[12], (const float*)d_in[16]};
  const float* bemb[3] = {(const float*)d_in[9],  (const float*)d_in[13], (const float*)d_in[17]};
  const float* gemb[3] = {(const float*)d_in[10], (const float*)d_in[14], (const float*)d_in[18]};
  const float* beemb[3]= {(const float*)d_in[11], (const float*)d_in[15], (const float*)d_in[19]};
  const float* gWl   = (const float*)d_in[20];
  const float* gWr   = (const float*)d_in[21];
  const float* gatt  = (const float*)d_in[22];
  const float* gbias = (const float*)d_in[23];

  const int NN[3]  = {NT, NW, NS};
  const int EC[5]  = {50000, 30000, 30000, 40000, 40000};
  const int STy[5] = {0, 0, 2, 1, 0};
  const int DTy[5] = {0, 2, 0, 0, 1};

  char* p = (char*)d_ws;
  auto alloc = [&](size_t bytes) -> void* {
    void* r = (void*)p;
    p += (bytes + 255) & ~(size_t)255;
    return r;
  };
  float* xc[3];  short* xcb[3];
  for (int k = 0; k < 3; ++k) xc[k]  = (float*)alloc((size_t)NN[k] * 64 * 4);
  for (int k = 0; k < 3; ++k) xcb[k] = (short*)alloc((size_t)NN[k] * 64 * 2);
  float* aggT0 = (float*)alloc((size_t)NT * 64 * 4);
  float* aggS  = (float*)alloc((size_t)NS * 64 * 4);
  float* aggT2 = (float*)alloc((size_t)NT * 64 * 4);
  float* aggT3 = (float*)alloc((size_t)NT * 64 * 4);
  float* aggW  = (float*)alloc((size_t)NW * 64 * 4);
  float* aggOf[5] = {aggT0, aggS, aggT2, aggT3, aggW};
  int* nxtAll = (int*)alloc((size_t)66000 * 4);
  int  nxtOff[5] = {0, NT, NT + NS, 2 * NT + NS, 3 * NT + NS};
  int* nxt[5]; for (int t = 0; t < 5; ++t) nxt[t] = nxtAll + nxtOff[t];
  int *rowp[5], *col[5];
  for (int t = 0; t < 5; ++t) {
    rowp[t] = (int*)alloc((size_t)(NN[DTy[t]] + 1) * 4);
    col[t]  = (int*)alloc((size_t)EC[t] * 4);
  }
  float* psum = (float*)alloc((size_t)104 * 64 * 4);
  float* pmax = (float*)alloc((size_t)104 * 64 * 4);
  short* Wlt  = (short*)alloc((size_t)10 * 16384 * 2);
  short* Wrt  = (short*)alloc((size_t)10 * 16384 * 2);
  float* ppk  = (float*)alloc((size_t)576 * 4);

  size_t used = (size_t)(p - (char*)d_ws);
  size_t fusedExtra = (size_t)132000 * 256 * 2 + (1 << 20);
  bool fused = (ws_size - used) >= fusedExtra;
  short *xlT[5], *xrT[5];
  if (fused) {
    for (int t = 0; t < 5; ++t) {
      xlT[t] = (short*)alloc((size_t)NN[STy[t]] * 256 * 2);
      xrT[t] = (short*)alloc((size_t)NN[DTy[t]] * 256 * 2);
    }
  } else {
    short* xlb = (short*)alloc((size_t)NT * 256 * 2);
    short* xrb = (short*)alloc((size_t)NT * 256 * 2);
    for (int t = 0; t < 5; ++t) { xlT[t] = xlb; xrT[t] = xrb; }
  }

  // 0) weight prep (bf16 + transpose) + nxt zero + param pack
  wprep_kernel<<<1280, 256, 0, stream>>>(gWl, gWr, Wlt, Wrt, nxtAll, 66000);
  packp_kernel<<<1, 64, 0, stream>>>(bemb[0], gemb[0], beemb[0],
                                     bemb[1], gemb[1], beemb[1],
                                     bemb[2], gemb[2], beemb[2], ppk);

  // 1) embedders (1 dispatch)
  embed_kernel<<<(26000 * 64 + 255) / 256, 256, 0, stream>>>(
      x_in[0], x_in[1], x_in[2], Wemb[0], Wemb[1], Wemb[2],
      ppk, ppk + 192, ppk + 384,
      xc[0], xc[1], xc[2], xcb[0], xcb[1], xcb[2]);

  // 2) CSR (3 dispatches)
  EdgeTab etab; etab.nseg = 5;
  int eb = 0;
  for (int t = 0; t < 5; ++t) {
    etab.s[t] = {ei[t], nxt[t], col[t], EC[t], eb};
    eb += (EC[t] + 255) / 256;
  }
  count_kernel<<<eb, 256, 0, stream>>>(etab);
  ScanTab stab;
  for (int t = 0; t < 5; ++t) { stab.cnt[t] = nxt[t]; stab.rowp[t] = rowp[t]; stab.n[t] = NN[DTy[t]]; }
  scan_kernel<<<5, 1024, 0, stream>>>(stab);
  fill_kernel<<<eb, 256, 0, stream>>>(etab);

  float* outT = (float*)d_out;
  float* outW = outT + (size_t)NT * 64;
  float* outS = outW + (size_t)NW * 64;
  float* gc   = outS + (size_t)NS * 64;

  // 3) GAT layers
  for (int l = 0; l < 2; ++l) {
    if (fused) {
      GemmTab gt; gt.nseg = 10;
      int gb = 0;
      for (int t = 0; t < 5; ++t) {
        size_t off = (size_t)(l * 5 + t);
        gt.s[2 * t + 0] = {xcb[STy[t]], Wlt + off * 16384, xlT[t], NN[STy[t]], gb};
        gb += (NN[STy[t]] + 63) / 64;
        gt.s[2 * t + 1] = {xcb[DTy[t]], Wrt + off * 16384, xrT[t], NN[DTy[t]], gb};
        gb += (NN[DTy[t]] + 63) / 64;
      }
      gemm_kernel<<<gb, 256, 0, stream>>>(gt);

      GatTab at; at.nseg = 5;
      int wv = 0;
      for (int t = 0; t < 5; ++t) {
        size_t off = (size_t)(l * 5 + t);
        at.s[t] = {rowp[t], col[t], xlT[t], xrT[t], gatt + off * 256, gbias + off * 64,
                   aggOf[t], NN[DTy[t]], wv};
        wv += NN[DTy[t]];
      }
      gat_kernel<<<(wv * 64 + 255) / 256, 256, 0, stream>>>(at);
    } else {
      for (int t = 0; t < 5; ++t) {
        size_t off = (size_t)(l * 5 + t);
        GemmTab gt; gt.nseg = 2;
        gt.s[0] = {xcb[STy[t]], Wlt + off * 16384, xlT[t], NN[STy[t]], 0};
        int gb = (NN[STy[t]] + 63) / 64;
        gt.s[1] = {xcb[DTy[t]], Wrt + off * 16384, xrT[t], NN[DTy[t]], gb};
        gb += (NN[DTy[t]] + 63) / 64;
        gemm_kernel<<<gb, 256, 0, stream>>>(gt);
        GatTab at; at.nseg = 1;
        at.s[0] = {rowp[t], col[t], xlT[t], xrT[t], gatt + off * 256, gbias + off * 64,
                   aggOf[t], NN[DTy[t]], 0};
        gat_kernel<<<((NN[DTy[t]] + 3) / 4), 256, 0, stream>>>(at);
      }
    }
    float* dT = (l == 1) ? outT : xc[0];
    float* dW = (l == 1) ? outW : xc[1];
    float* dS = (l == 1) ? outS : xc[2];
    unsigned* bT = (l == 1) ? nullptr : (unsigned*)xcb[0];
    unsigned* bW = (l == 1) ? nullptr : (unsigned*)xcb[1];
    unsigned* bS = (l == 1) ? nullptr : (unsigned*)xcb[2];
    combine_kernel<<<(26000 * 16 + 255) / 256, 256, 0, stream>>>(
        (const float4*)aggT0, (const float4*)aggT2, (const float4*)aggT3,
        (const float4*)aggW, (const float4*)aggS,
        (const float4*)xc[0], (const float4*)xc[1], (const float4*)xc[2],
        (float4*)dT, (float4*)dW, (float4*)dS, bT, bW, bS);
  }

  // 4) global pooling
  pool1_kernel<<<104, 256, 0, stream>>>(outT, outW, outS, psum, pmax);
  pool2_kernel<<<3, 256, 0, stream>>>(psum, pmax, gc);
}

// Round 7
// 236.019 us; speedup vs baseline: 1.0759x; 1.0759x over previous
//
#include <hip/hip_runtime.h>
#include <math.h>

#define NT 20000
#define NW 5000
#define NS 1000

typedef __attribute__((ext_vector_type(8))) short bf16x8;
typedef __attribute__((ext_vector_type(4))) float f32x4;

// combine grid segmentation (float4 elements, 256/block, per-type aligned)
#define CB_T 1250   // 20000*16/256
#define CB_W 313    // ceil(5000*16/256)
#define CB_S 63     // ceil(1000*16/256)
#define CB_ALL 1626

// ---------------- tables ----------------
struct GemmSeg { const short* X; const short* Wt; short* Y; int N; int blk0; };
struct GemmTab { GemmSeg s[10]; int nseg; };

struct GatTab {
  const int* rowp[5]; const int* col[5];
  const short* xl[5]; const short* xr[5];
  const float* att; const float* bias;   // layer-offset folded in
  float* aggT; float* aggW; float* aggS;
};

struct EdgeSeg { const int* ei; int* cnt; int* col; int E; int blk0; };
struct EdgeTab { EdgeSeg s[5]; int nseg; };

struct ScanTab { int* cnt[5]; int* rowp[5]; int n[5]; };

struct Mega0 {
  const float *xT, *xW, *xS, *WT, *WW, *WS;
  const float *bT, *gT, *beT, *bW, *gW, *beW, *bS, *gS, *beS;
  float *yT, *yW, *yS; short *ybT, *ybW, *ybS;
  const float *gWl, *gWr; short *Wlt, *Wrt; int* nxtAll;
};

// ---------------- helpers ----------------
__device__ __forceinline__ float wsum64(float v) {
  #pragma unroll
  for (int o = 32; o > 0; o >>= 1) v += __shfl_xor(v, o, 64);
  return v;
}
__device__ __forceinline__ short f2b(float f) {   // f32 -> bf16 RNE
  unsigned u = __float_as_uint(f);
  unsigned r = (u + 0x7FFFu + ((u >> 16) & 1u)) >> 16;
  return (short)(unsigned short)r;
}
__device__ __forceinline__ float blo(unsigned x) { return __uint_as_float(x << 16); }
__device__ __forceinline__ float bhi(unsigned x) { return __uint_as_float(x & 0xFFFF0000u); }

// ---------------- mega0: embed (blocks 0..6499) | wprep+zero (6500..7779) ------------
// NOTE: count must NOT live in this dispatch — it reads nxtAll which is zeroed here,
// and blocks within a dispatch have no ordering (R6 bug).
__global__ void mega0_kernel(Mega0 M) {
  int b = blockIdx.x;
  if (b < 6500) {
    // ---- embed: one wave per node
    int gid = b * 256 + threadIdx.x;
    int wid = gid >> 6, lane = gid & 63;
    const float *x, *W, *bb, *gg, *be; float* y; short* yb; int FD, n;
    if (wid < NT)            { x = M.xT; W = M.WT; bb = M.bT; gg = M.gT; be = M.beT; y = M.yT; yb = M.ybT; FD = 16; n = wid; }
    else if (wid < NT + NW)  { x = M.xW; W = M.WW; bb = M.bW; gg = M.gW; be = M.beW; y = M.yW; yb = M.ybW; FD = 12; n = wid - NT; }
    else                     { x = M.xS; W = M.WS; bb = M.bS; gg = M.gS; be = M.beS; y = M.yS; yb = M.ybS; FD = 10; n = wid - NT - NW; }
    const float* xr = x + (size_t)n * FD;
    float acc = bb[lane];
    for (int k = 0; k < FD; ++k) acc = fmaf(xr[k], W[k * 64 + lane], acc);
    float m = wsum64(acc) * (1.f / 64.f);
    float d = acc - m;
    float v = wsum64(d * d) * (1.f / 64.f);
    float o = d * rsqrtf(v + 1e-5f) * gg[lane] + be[lane];
    o = fmaxf(o, 0.f);
    y[(size_t)n * 64 + lane] = o;
    yb[(size_t)n * 64 + lane] = f2b(o);
  } else {
    // ---- wprep: f32 [k][col] -> bf16 [col][k]; zero nxtAll
    int idx = (b - 6500) * 256 + threadIdx.x;   // 0..327679
    if (idx < 66000) M.nxtAll[idx] = 0;
    int side = idx >= 163840;
    int j = idx - side * 163840;
    int m = j >> 14, e = j & 16383;
    int k = e >> 8, colv = e & 255;
    const float* src = side ? M.gWr : M.gWl;
    short* dst = side ? M.Wrt : M.Wlt;
    dst[m * 16384 + colv * 64 + k] = f2b(src[m * 16384 + e]);
  }
}

// ---------------- CSR: count / scan / fill ----------------
__global__ void count_kernel(EdgeTab tab) {
  int b = blockIdx.x, si = 0;
  for (int i = 1; i < tab.nseg; ++i) if (b >= tab.s[i].blk0) si = i;
  EdgeSeg sg = tab.s[si];
  int e = (b - sg.blk0) * 256 + threadIdx.x;
  if (e < sg.E) atomicAdd(&sg.cnt[sg.ei[sg.E + e]], 1);
}

__global__ void scan_kernel(ScanTab tab) {
  int t = blockIdx.x;
  int* cnt = tab.cnt[t]; int* rowp = tab.rowp[t]; int n = tab.n[t];
  __shared__ int wsums[16];
  __shared__ int carry_s;
  int tid = threadIdx.x, lane = tid & 63, w = tid >> 6;
  if (tid == 0) carry_s = 0;
  __syncthreads();
  for (int base = 0; base < n; base += 1024) {
    int i = base + tid;
    int v = (i < n) ? cnt[i] : 0;
    int s = v;
    #pragma unroll
    for (int o = 1; o < 64; o <<= 1) { int x = __shfl_up(s, o, 64); if (lane >= o) s += x; }
    if (lane == 63) wsums[w] = s;
    __syncthreads();
    if (w == 0 && lane < 16) {
      int x = wsums[lane];
      #pragma unroll
      for (int o = 1; o < 16; o <<= 1) { int y = __shfl_up(x, o, 16); if (lane >= o) x += y; }
      wsums[lane] = x;
    }
    __syncthreads();
    int carry   = carry_s;
    int waveoff = (w == 0) ? 0 : wsums[w - 1];
    int exc     = carry + waveoff + s - v;
    if (i < n) { rowp[i] = exc; cnt[i] = exc; }
    __syncthreads();
    if (tid == 0) carry_s += wsums[15];
    __syncthreads();
  }
  if (threadIdx.x == 0) rowp[n] = carry_s;
}

__global__ void fill_kernel(EdgeTab tab) {
  int b = blockIdx.x, si = 0;
  for (int i = 1; i < tab.nseg; ++i) if (b >= tab.s[i].blk0) si = i;
  EdgeSeg sg = tab.s[si];
  int e = (b - sg.blk0) * 256 + threadIdx.x;
  if (e >= sg.E) return;
  int s = sg.ei[e], d = sg.ei[sg.E + e];
  int pos = atomicAdd(&sg.cnt[d], 1);
  sg.col[pos] = s;
}

// ---------------- MFMA GEMM: Y[N,256](bf16) = X[N,64](bf16) @ W[64,256] ----------------
__global__ __launch_bounds__(256) void gemm_kernel(GemmTab tab) {
  __shared__ short lds[4096 + 16896];
  int b = blockIdx.x, si = 0;
  for (int i = 1; i < tab.nseg; ++i) if (b >= tab.s[i].blk0) si = i;
  GemmSeg sg = tab.s[si];
  int r0 = (b - sg.blk0) * 64;
  int tid = threadIdx.x;
  #pragma unroll
  for (int it = 0; it < 2; ++it) {              // stage X tile
    int idx = it * 256 + tid;
    int row = idx >> 3, kq = idx & 7;
    bf16x8 v = {0, 0, 0, 0, 0, 0, 0, 0};
    if (r0 + row < sg.N) v = *(const bf16x8*)&sg.X[(size_t)(r0 + row) * 64 + kq * 8];
    *(bf16x8*)&lds[(row * 8 + (kq ^ (row & 7))) * 8] = v;
  }
  #pragma unroll
  for (int it = 0; it < 8; ++it) {              // stage Wt
    int idx = it * 256 + tid;
    int col = idx >> 3, kq = idx & 7;
    bf16x8 v = *(const bf16x8*)&sg.Wt[col * 64 + kq * 8];
    *(bf16x8*)&lds[4096 + (col * 8 + (kq ^ (col & 7))) * 8] = v;
  }
  __syncthreads();
  int lane = tid & 63, wv = tid >> 6;
  int r = lane & 15, hk = lane >> 4;
  f32x4 acc[4][4];
  #pragma unroll
  for (int rt = 0; rt < 4; ++rt)
    #pragma unroll
    for (int ct = 0; ct < 4; ++ct) acc[rt][ct] = (f32x4){0.f, 0.f, 0.f, 0.f};
  #pragma unroll
  for (int kk = 0; kk < 2; ++kk) {
    int kq = kk * 4 + hk;
    bf16x8 a[4], bb[4];
    #pragma unroll
    for (int rt = 0; rt < 4; ++rt) {
      int row = rt * 16 + r;
      a[rt] = *(const bf16x8*)&lds[(row * 8 + (kq ^ (row & 7))) * 8];
    }
    #pragma unroll
    for (int ct = 0; ct < 4; ++ct) {
      int col = wv * 64 + ct * 16 + r;
      bb[ct] = *(const bf16x8*)&lds[4096 + (col * 8 + (kq ^ (col & 7))) * 8];
    }
    #pragma unroll
    for (int rt = 0; rt < 4; ++rt)
      #pragma unroll
      for (int ct = 0; ct < 4; ++ct)
        acc[rt][ct] = __builtin_amdgcn_mfma_f32_16x16x32_bf16(a[rt], bb[ct], acc[rt][ct], 0, 0, 0);
  }
  __syncthreads();                               // LDS reuse: C repack
  #pragma unroll
  for (int rt = 0; rt < 4; ++rt)
    #pragma unroll
    for (int j = 0; j < 4; ++j) {
      int rowl = rt * 16 + hk * 4 + j;           // C/D: col=lane&15, row=(lane>>4)*4+reg
      #pragma unroll
      for (int ct = 0; ct < 4; ++ct)
        lds[rowl * 264 + wv * 64 + ct * 16 + r] = f2b(acc[rt][ct][j]);
    }
  __syncthreads();
  #pragma unroll
  for (int it = 0; it < 8; ++it) {               // coalesced bf16x8 stores
    int idx = it * 256 + tid;
    int row = idx >> 5, v8 = idx & 31;
    if (r0 + row < sg.N) {
      bf16x8 v = *(const bf16x8*)&lds[row * 264 + v8 * 8];
      *(bf16x8*)&sg.Y[(size_t)(r0 + row) * 256 + v8 * 8] = v;
    }
  }
}

// ---------------- GATv2: wave per dst NODE; all its relations in one wave ----------------
__global__ void gat_kernel(GatTab tab) {
  int gwave = (blockIdx.x * blockDim.x + threadIdx.x) >> 6;
  int lane  = threadIdx.x & 63;
  int h = lane >> 4, lig = lane & 15;
  int nrel, n; float* agg;
  int rels[3];
  if (gwave < NT)            { nrel = 3; rels[0] = 0; rels[1] = 2; rels[2] = 3; n = gwave; agg = tab.aggT; }
  else if (gwave < NT + NW)  { nrel = 1; rels[0] = 4; rels[1] = 4; rels[2] = 4; n = gwave - NT; agg = tab.aggW; }
  else if (gwave < NT + NW + NS) { nrel = 1; rels[0] = 1; rels[1] = 1; rels[2] = 1; n = gwave - NT - NW; agg = tab.aggS; }
  else return;
  float o0 = 0.f, o1 = 0.f, o2 = 0.f, o3 = 0.f;   // sum over relations of per-head-normalized output
  for (int ri = 0; ri < nrel; ++ri) {
    int r = rels[ri];
    int beg = tab.rowp[r][n], end = tab.rowp[r][n + 1];
    const short* xl = tab.xl[r];
    const int* colp = tab.col[r];
    uint2 xru = *(const uint2*)&tab.xr[r][(size_t)n * 256 + h * 64 + lig * 4];
    float4 a4 = *(const float4*)&tab.att[r * 256 + h * 64 + lig * 4];
    float xr0 = blo(xru.x), xr1 = bhi(xru.x), xr2 = blo(xru.y), xr3 = bhi(xru.y);
    if (end > beg) {
      float den = 0.f, c0 = 0.f, c1 = 0.f, c2 = 0.f, c3 = 0.f;
      int sNxt = colp[beg];
      uint2 w = *(const uint2*)&xl[(size_t)sNxt * 256 + h * 64 + lig * 4];
      if (beg + 1 < end) sNxt = colp[beg + 1];
      for (int i = beg; i < end; ++i) {
        uint2 wc = w;
        if (i + 1 < end) w = *(const uint2*)&xl[(size_t)sNxt * 256 + h * 64 + lig * 4];
        if (i + 2 < end) sNxt = colp[i + 2];
        float f0 = blo(wc.x), f1 = bhi(wc.x), f2v = blo(wc.y), f3 = bhi(wc.y);
        float vx = f0 + xr0, vy = f1 + xr1, vz = f2v + xr2, vw = f3 + xr3;
        vx = fmaxf(vx, 0.2f * vx); vy = fmaxf(vy, 0.2f * vy);
        vz = fmaxf(vz, 0.2f * vz); vw = fmaxf(vw, 0.2f * vw);
        float dd = fmaf(vx, a4.x, fmaf(vy, a4.y, fmaf(vz, a4.z, vw * a4.w)));
        dd += __shfl_xor(dd, 1, 64);
        dd += __shfl_xor(dd, 2, 64);
        dd += __shfl_xor(dd, 4, 64);
        dd += __shfl_xor(dd, 8, 64);
        float e = __expf(dd);                    // softmax shift-invariant; logits O(10)
        den += e;
        c0 = fmaf(e, f0, c0); c1 = fmaf(e, f1, c1);
        c2 = fmaf(e, f2v, c2); c3 = fmaf(e, f3, c3);
      }
      float inv = 1.f / den;
      o0 = fmaf(c0, inv, o0); o1 = fmaf(c1, inv, o1);
      o2 = fmaf(c2, inv, o2); o3 = fmaf(c3, inv, o3);
    }
  }
  o0 += __shfl_xor(o0, 16, 64); o0 += __shfl_xor(o0, 32, 64);
  o1 += __shfl_xor(o1, 16, 64); o1 += __shfl_xor(o1, 32, 64);
  o2 += __shfl_xor(o2, 16, 64); o2 += __shfl_xor(o2, 32, 64);
  o3 += __shfl_xor(o3, 16, 64); o3 += __shfl_xor(o3, 32, 64);
  if (lane < 16) {
    float4 bs = make_float4(0.f, 0.f, 0.f, 0.f);
    for (int ri = 0; ri < nrel; ++ri) {
      float4 b4 = *(const float4*)&tab.bias[rels[ri] * 64 + lane * 4];
      bs.x += b4.x; bs.y += b4.y; bs.z += b4.z; bs.w += b4.w;
    }
    float4 res;
    res.x = fmaf(0.25f, o0, bs.x); res.y = fmaf(0.25f, o1, bs.y);
    res.z = fmaf(0.25f, o2, bs.z); res.w = fmaf(0.25f, o3, bs.w);
    *(float4*)&agg[(size_t)n * 64 + lane * 4] = res;
  }
}

// ---------------- combine (+optional fused pool partials) ----------------
template <int POOL>
__global__ __launch_bounds__(256) void combine_kernel(
    const float4* __restrict__ aT, const float4* __restrict__ aW, const float4* __restrict__ aS,
    const float4* __restrict__ xT, const float4* __restrict__ xW, const float4* __restrict__ xS,
    float4* __restrict__ oT, float4* __restrict__ oW, float4* __restrict__ oS,
    unsigned* __restrict__ bT, unsigned* __restrict__ bW, unsigned* __restrict__ bS,
    float4* __restrict__ psum, float4* __restrict__ pmax) {
  int b = blockIdx.x, tid = threadIdx.x;
  const float4 *a, *x; float4* o; unsigned* bo; int n4, local;
  if (b < CB_T)              { a = aT; x = xT; o = oT; bo = bT; n4 = NT * 16; local = b; }
  else if (b < CB_T + CB_W)  { a = aW; x = xW; o = oW; bo = bW; n4 = NW * 16; local = b - CB_T; }
  else                       { a = aS; x = xS; o = oS; bo = bS; n4 = NS * 16; local = b - CB_T - CB_W; }
  int j = local * 256 + tid;
  bool valid = j < n4;
  float4 r = make_float4(0.f, 0.f, 0.f, 0.f);
  if (valid) {
    float4 av = a[j], xv = x[j];
    r.x = fmaxf(av.x, 0.f) + xv.x; r.y = fmaxf(av.y, 0.f) + xv.y;
    r.z = fmaxf(av.z, 0.f) + xv.z; r.w = fmaxf(av.w, 0.f) + xv.w;
    o[j] = r;
    if (POOL == 0 && bo) {
      unsigned lo = (unsigned)(unsigned short)f2b(r.x) | ((unsigned)(unsigned short)f2b(r.y) << 16);
      unsigned hi = (unsigned)(unsigned short)f2b(r.z) | ((unsigned)(unsigned short)f2b(r.w) << 16);
      bo[j * 2] = lo; bo[j * 2 + 1] = hi;
    }
  }
  if (POOL) {
    float4 s = r;
    float4 m = valid ? r : make_float4(-3e38f, -3e38f, -3e38f, -3e38f);
    #pragma unroll
    for (int off = 16; off <= 32; off <<= 1) {
      s.x += __shfl_xor(s.x, off, 64); s.y += __shfl_xor(s.y, off, 64);
      s.z += __shfl_xor(s.z, off, 64); s.w += __shfl_xor(s.w, off, 64);
      m.x = fmaxf(m.x, __shfl_xor(m.x, off, 64)); m.y = fmaxf(m.y, __shfl_xor(m.y, off, 64));
      m.z = fmaxf(m.z, __shfl_xor(m.z, off, 64)); m.w = fmaxf(m.w, __shfl_xor(m.w, off, 64));
    }
    __shared__ float4 ls[4][16], lm[4][16];
    int w = tid >> 6, q = tid & 15;
    if (((tid >> 4) & 3) == 0) { ls[w][q] = s; lm[w][q] = m; }
    __syncthreads();
    if (tid < 16) {
      float4 S = ls[0][tid], M = lm[0][tid];
      #pragma unroll
      for (int i = 1; i < 4; ++i) {
        float4 s2 = ls[i][tid], m2 = lm[i][tid];
        S.x += s2.x; S.y += s2.y; S.z += s2.z; S.w += s2.w;
        M.x = fmaxf(M.x, m2.x); M.y = fmaxf(M.y, m2.y);
        M.z = fmaxf(M.z, m2.z); M.w = fmaxf(M.w, m2.w);
      }
      psum[b * 16 + tid] = S;
      pmax[b * 16 + tid] = M;
    }
  }
}

// ---------------- pool stage 2 ----------------
// gc layout: [s_mean, t_mean, w_mean, s_max, t_max, w_max] (64 each)
__global__ void pool2_kernel(const float* __restrict__ psum,
                             const float* __restrict__ pmax,
                             float* __restrict__ gc) {
  int b = blockIdx.x;  // 0 station, 1 task, 2 worker
  int lane = threadIdx.x & 63, w = threadIdx.x >> 6;
  int off, cnt, N, mi;
  if (b == 0)      { off = CB_T + CB_W; cnt = CB_S; N = NS; mi = 0;   }
  else if (b == 1) { off = 0;           cnt = CB_T; N = NT; mi = 64;  }
  else             { off = CB_T;        cnt = CB_W; N = NW; mi = 128; }
  float s = 0.f, mx = -3e38f;
  for (int i = w; i < cnt; i += 16) {
    s += psum[(size_t)(off + i) * 64 + lane];
    mx = fmaxf(mx, pmax[(size_t)(off + i) * 64 + lane]);
  }
  __shared__ float ss[16][64], sm[16][64];
  ss[w][lane] = s; sm[w][lane] = mx;
  __syncthreads();
  if (w == 0) {
    #pragma unroll
    for (int i = 1; i < 16; ++i) { s += ss[i][lane]; mx = fmaxf(mx, sm[i][lane]); }
    gc[mi + lane] = s / (float)N;
    gc[192 + mi + lane] = mx;
  }
}

// ---------------- driver ----------------
extern "C" void kernel_launch(void* const* d_in, const int* in_sizes, int n_in,
                              void* d_out, int out_size, void* d_ws, size_t ws_size,
                              hipStream_t stream) {
  const float* x_in[3] = {(const float*)d_in[0], (const float*)d_in[1], (const float*)d_in[2]};
  const int*   ei[5]   = {(const int*)d_in[3], (const int*)d_in[4], (const int*)d_in[5],
                          (const int*)d_in[6], (const int*)d_in[7]};
  const float* Wemb[3] = {(const float*)d_in[8],  (const float*)d_in[12], (const float*)d_in[16]};
  const float* bemb[3] = {(const float*)d_in[9],  (const float*)d_in[13], (const float*)d_in[17]};
  const float* gemb[3] = {(const float*)d_in[10], (const float*)d_in[14], (const float*)d_in[18]};
  const float* beemb[3]= {(const float*)d_in[11], (const float*)d_in[15], (const float*)d_in[19]};
  const float* gWl   = (const float*)d_in[20];
  const float* gWr   = (const float*)d_in[21];
  const float* gatt  = (const float*)d_in[22];
  const float* gbias = (const float*)d_in[23];

  const int NN[3]  = {NT, NW, NS};
  const int EC[5]  = {50000, 30000, 30000, 40000, 40000};
  const int STy[5] = {0, 0, 2, 1, 0};
  const int DTy[5] = {0, 2, 0, 0, 1};

  char* p = (char*)d_ws;
  auto alloc = [&](size_t bytes) -> void* {
    void* r = (void*)p;
    p += (bytes + 255) & ~(size_t)255;
    return r;
  };
  float* xc[3];  short* xcb[3];
  for (int k = 0; k < 3; ++k) xc[k]  = (float*)alloc((size_t)NN[k] * 64 * 4);
  for (int k = 0; k < 3; ++k) xcb[k] = (short*)alloc((size_t)NN[k] * 64 * 2);
  float* aggT = (float*)alloc((size_t)NT * 64 * 4);
  float* aggW = (float*)alloc((size_t)NW * 64 * 4);
  float* aggS = (float*)alloc((size_t)NS * 64 * 4);
  int* nxtAll = (int*)alloc((size_t)66000 * 4);
  int  nxtOff[5] = {0, NT, NT + NS, 2 * NT + NS, 3 * NT + NS};
  int* nxt[5]; for (int t = 0; t < 5; ++t) nxt[t] = nxtAll + nxtOff[t];
  int *rowp[5], *col[5];
  for (int t = 0; t < 5; ++t) {
    rowp[t] = (int*)alloc((size_t)(NN[DTy[t]] + 1) * 4);
    col[t]  = (int*)alloc((size_t)EC[t] * 4);
  }
  float* psum = (float*)alloc((size_t)CB_ALL * 64 * 4);
  float* pmax = (float*)alloc((size_t)CB_ALL * 64 * 4);
  short* Wlt  = (short*)alloc((size_t)10 * 16384 * 2);
  short* Wrt  = (short*)alloc((size_t)10 * 16384 * 2);
  short *xlT[5], *xrT[5];
  for (int t = 0; t < 5; ++t) {
    xlT[t] = (short*)alloc((size_t)NN[STy[t]] * 256 * 2);
    xrT[t] = (short*)alloc((size_t)NN[DTy[t]] * 256 * 2);
  }

  // edge table (blk0 relative to count/fill grids)
  EdgeTab etab; etab.nseg = 5;
  int eb = 0;
  for (int t = 0; t < 5; ++t) {
    etab.s[t] = {ei[t], nxt[t], col[t], EC[t], eb};
    eb += (EC[t] + 255) / 256;
  }

  // 0) mega0: embed | wprep+zero (count kept separate — ordering!)
  Mega0 M;
  M.xT = x_in[0]; M.xW = x_in[1]; M.xS = x_in[2];
  M.WT = Wemb[0]; M.WW = Wemb[1]; M.WS = Wemb[2];
  M.bT = bemb[0]; M.gT = gemb[0]; M.beT = beemb[0];
  M.bW = bemb[1]; M.gW = gemb[1]; M.beW = beemb[1];
  M.bS = bemb[2]; M.gS = gemb[2]; M.beS = beemb[2];
  M.yT = xc[0]; M.yW = xc[1]; M.yS = xc[2];
  M.ybT = xcb[0]; M.ybW = xcb[1]; M.ybS = xcb[2];
  M.gWl = gWl; M.gWr = gWr; M.Wlt = Wlt; M.Wrt = Wrt; M.nxtAll = nxtAll;
  mega0_kernel<<<7780, 256, 0, stream>>>(M);

  // 1) CSR: count, scan, fill
  count_kernel<<<eb, 256, 0, stream>>>(etab);
  ScanTab stab;
  for (int t = 0; t < 5; ++t) { stab.cnt[t] = nxt[t]; stab.rowp[t] = rowp[t]; stab.n[t] = NN[DTy[t]]; }
  scan_kernel<<<5, 1024, 0, stream>>>(stab);
  fill_kernel<<<eb, 256, 0, stream>>>(etab);

  float* outT = (float*)d_out;
  float* outW = outT + (size_t)NT * 64;
  float* outS = outW + (size_t)NW * 64;
  float* gc   = outS + (size_t)NS * 64;

  // 2) GAT layers
  for (int l = 0; l < 2; ++l) {
    GemmTab gt; gt.nseg = 10;
    int gb = 0;
    for (int t = 0; t < 5; ++t) {
      size_t off = (size_t)(l * 5 + t);
      gt.s[2 * t + 0] = {xcb[STy[t]], Wlt + off * 16384, xlT[t], NN[STy[t]], gb};
      gb += (NN[STy[t]] + 63) / 64;
      gt.s[2 * t + 1] = {xcb[DTy[t]], Wrt + off * 16384, xrT[t], NN[DTy[t]], gb};
      gb += (NN[DTy[t]] + 63) / 64;
    }
    gemm_kernel<<<gb, 256, 0, stream>>>(gt);

    GatTab at;
    for (int t = 0; t < 5; ++t) {
      at.rowp[t] = rowp[t]; at.col[t] = col[t];
      at.xl[t] = xlT[t]; at.xr[t] = xrT[t];
    }
    at.att  = gatt  + (size_t)l * 5 * 256;
    at.bias = gbias + (size_t)l * 5 * 64;
    at.aggT = aggT; at.aggW = aggW; at.aggS = aggS;
    gat_kernel<<<(26000 * 64 + 255) / 256, 256, 0, stream>>>(at);

    if (l == 0) {
      combine_kernel<0><<<CB_ALL, 256, 0, stream>>>(
          (const float4*)aggT, (const float4*)aggW, (const float4*)aggS,
          (const float4*)xc[0], (const float4*)xc[1], (const float4*)xc[2],
          (float4*)xc[0], (float4*)xc[1], (float4*)xc[2],
          (unsigned*)xcb[0], (unsigned*)xcb[1], (unsigned*)xcb[2],
          nullptr, nullptr);
    } else {
      combine_kernel<1><<<CB_ALL, 256, 0, stream>>>(
          (const float4*)aggT, (const float4*)aggW, (const float4*)aggS,
          (const float4*)xc[0], (const float4*)xc[1], (const float4*)xc[2],
          (float4*)outT, (float4*)outW, (float4*)outS,
          nullptr, nullptr, nullptr,
          (float4*)psum, (float4*)pmax);
    }
  }

  // 3) final pool reduce
  pool2_kernel<<<3, 1024, 0, stream>>>(psum, pmax, gc);
}